// Round 3
// baseline (581.569 us; speedup 1.0000x reference)
//
#include <hip/hip_runtime.h>
#include <hip/hip_bf16.h>

// Problem constants
#define NN 240        // rows (tokens)
#define CC 6144       // channels
#define DD 3072       // head dim
#define C3 18432      // 3*C
#define HH 2          // heads

typedef __attribute__((ext_vector_type(8))) short bf16x8;
typedef __attribute__((ext_vector_type(4))) float f32x4;
typedef unsigned short ushort_t;

static __device__ __forceinline__ unsigned short f2bf(float f) {
    __hip_bfloat16 h = __float2bfloat16(f);
    return __builtin_bit_cast(unsigned short, h);
}

// global -> LDS direct DMA, 16 B per lane. LDS dest must be wave-uniform.
#define GLDS16(g, l) __builtin_amdgcn_global_load_lds( \
    (const __attribute__((address_space(1))) void*)(g), \
    (__attribute__((address_space(3))) void*)(l), 16, 0, 0)

// C[M=240 x N] = A_bf16[256 x K] * B_fp32[N x K]^T, split-K over KS chunks.
// kc==0 writes C0+z*sC0z, kc>0 writes CP partials. 256x128 tile, BK=64,
// 8 waves (4Mx2N) of 64x64. A,B staged via global_load_lds with per-lane
// XOR-swizzled SOURCE addresses (LDS linear) + swizzled ds_read.
__global__ __launch_bounds__(512, 2)
void gemm_as(const ushort_t* __restrict__ Ab, int lda, long long sAz,
             const float* __restrict__ B, int ldb, long long sBz,
             float* __restrict__ C0, long long sC0z,
             float* __restrict__ CP, long long sCPz,
             int ldc, int N, int Kc, int KS) {
    __shared__ ushort_t sA[2][256 * 64];   // 2 x 32 KB bf16
    __shared__ float    sB[2][128 * 64];   // 2 x 32 KB fp32

    const int zc = blockIdx.z;
    const int z = zc / KS, kc = zc % KS;
    const ushort_t* Abase = Ab + (size_t)z * sAz;
    const float*    Bbase = B + (size_t)z * sBz;
    float* Cw = (kc == 0) ? (C0 + (size_t)z * sC0z)
                          : (CP + (size_t)(z * (KS - 1) + kc - 1) * sCPz);

    const int n0 = blockIdx.x * 128;
    const int tid = threadIdx.x, lane = tid & 63, wid = tid >> 6;
    const int wm = wid >> 1, wn = wid & 1;
    const int l16 = lane & 15, lk = lane >> 4;

    // A source: chunk c=wid*4+i covers LDS rows c*8..c*8+8 (128 B each).
    // Lane l -> row c*8+(l>>3), 16B slot (l&7); content must be
    // A[row][slot ^ (row&7)] so the XOR'd ds_read recovers linear k.
    const int arow = wid * 32 + (lane >> 3);
    const ushort_t* ap = Abase + (size_t)arow * lda + (size_t)kc * Kc
                         + ((lane & 7) ^ (lane >> 3)) * 8;
    const long long astep = 8LL * lda;     // +8 rows per i

    // B source: chunk c covers LDS rows c*4..c*4+4 (256 B each).
    // Lane l -> row c*4+(l>>4), 16B pos (l&15); XOR on 32B granule.
    const char* bbase = (const char*)Bbase;
    long long bo[4];
#pragma unroll
    for (int i = 0; i < 4; ++i) {
        int lr = wid * 16 + i * 4 + (lane >> 4);      // local row 0..127
        bo[i] = ((long long)(n0 + lr) * ldb + (long long)kc * Kc) * 4
                + (((lane & 15) * 16) ^ ((lr & 7) << 5));
    }

    const int nt = Kc / 64;
    f32x4 acc[4][4] = {};

    // prologue: stage tile 0 into buffer 0
#pragma unroll
    for (int i = 0; i < 4; ++i)
        GLDS16(ap + i * astep, &sA[0][(wid * 4 + i) * 512]);
#pragma unroll
    for (int i = 0; i < 4; ++i)
        GLDS16(bbase + bo[i], &sB[0][(wid * 4 + i) * 256]);

    for (int t = 0; t < nt; ++t) {
        asm volatile("s_waitcnt vmcnt(0)" ::: "memory");
        __builtin_amdgcn_s_barrier();
        __builtin_amdgcn_sched_barrier(0);
        if (t + 1 < nt) {                   // issue next tile's DMA now;
            int nb = (t + 1) & 1;           // it completes under the MFMA phase
            const ushort_t* a = ap + (size_t)(t + 1) * 64;
#pragma unroll
            for (int i = 0; i < 4; ++i)
                GLDS16(a + i * astep, &sA[nb][(wid * 4 + i) * 512]);
            const char* bB = bbase + (size_t)(t + 1) * 256;
#pragma unroll
            for (int i = 0; i < 4; ++i)
                GLDS16(bB + bo[i], &sB[nb][(wid * 4 + i) * 256]);
        }
        const char* As = (const char*)sA[t & 1];
        const char* Bs = (const char*)sB[t & 1];
#pragma unroll
        for (int ks = 0; ks < 2; ++ks) {
            bf16x8 af[4], bfr[4];
#pragma unroll
            for (int mt = 0; mt < 4; ++mt) {
                int row = wm * 64 + mt * 16 + l16;
                int boff = row * 128 + (((ks * 4 + lk) * 16) ^ ((row & 7) << 4));
                af[mt] = *(const bf16x8*)(As + boff);
            }
#pragma unroll
            for (int nf = 0; nf < 4; ++nf) {
                int row = wn * 64 + nf * 16 + l16;
                int b0 = row * 256 + ((ks * 128 + lk * 32) ^ ((row & 7) << 5));
                float4 v0 = *(const float4*)(Bs + b0);
                float4 v1 = *(const float4*)(Bs + b0 + 16);
                bf16x8 r;
                r[0] = (short)f2bf(v0.x); r[1] = (short)f2bf(v0.y);
                r[2] = (short)f2bf(v0.z); r[3] = (short)f2bf(v0.w);
                r[4] = (short)f2bf(v1.x); r[5] = (short)f2bf(v1.y);
                r[6] = (short)f2bf(v1.z); r[7] = (short)f2bf(v1.w);
                bfr[nf] = r;
            }
            __builtin_amdgcn_s_setprio(1);
#pragma unroll
            for (int mt = 0; mt < 4; ++mt)
#pragma unroll
                for (int nf = 0; nf < 4; ++nf)
                    acc[mt][nf] = __builtin_amdgcn_mfma_f32_16x16x32_bf16(
                        af[mt], bfr[nf], acc[mt][nf], 0, 0, 0);
            __builtin_amdgcn_s_setprio(0);
        }
    }

    // Epilogue: fragment row = lk*4+j, col = l16
#pragma unroll
    for (int mt = 0; mt < 4; ++mt) {
#pragma unroll
        for (int j = 0; j < 4; ++j) {
            int grow = wm * 64 + mt * 16 + lk * 4 + j;
            if (grow < NN) {
#pragma unroll
                for (int nf = 0; nf < 4; ++nf) {
                    int gcol = n0 + wn * 64 + nf * 16 + l16;
                    if (gcol < N)
                        Cw[(size_t)grow * ldc + gcol] = acc[mt][nf][j];
                }
            }
        }
    }
}

// xb = bf16(x) padded to 256 rows; zero pad rows (240..255) of qb and preb.
__global__ __launch_bounds__(256)
void convert_kernel(const float* __restrict__ x, ushort_t* __restrict__ xb,
                    ushort_t* __restrict__ qb, ushort_t* __restrict__ preb) {
    int id = blockIdx.x * 256 + threadIdx.x;
    if (id < 196608) {                       // 256*6144/8
        int row = id / 768, c8 = id % 768;
        bf16x8 o = {};
        if (row < NN) {
            const float* p = x + (size_t)row * CC + c8 * 8;
            float4 a = *(const float4*)p, b = *(const float4*)(p + 4);
            o[0] = (short)f2bf(a.x); o[1] = (short)f2bf(a.y);
            o[2] = (short)f2bf(a.z); o[3] = (short)f2bf(a.w);
            o[4] = (short)f2bf(b.x); o[5] = (short)f2bf(b.y);
            o[6] = (short)f2bf(b.z); o[7] = (short)f2bf(b.w);
        }
        *(bf16x8*)(xb + (size_t)row * CC + c8 * 8) = o;
    } else if (id < 196608 + 24576) {
        int j = id - 196608;                 // pad rows: 16*6144/8 = 12288 each
        ushort_t* tgt = (j < 12288) ? qb : preb;
        int jj = (j < 12288) ? j : j - 12288;
        bf16x8 zo = {};
        *(bf16x8*)(tgt + (size_t)NN * CC + (size_t)jj * 8) = zo;
    }
}

// qkv += partial (in place); also emit bf16 Q copy (cols < 6144).
__global__ __launch_bounds__(256)
void reduce_qkv(float4* __restrict__ q4, const float4* __restrict__ p4,
                ushort_t* __restrict__ qb) {
    int i = blockIdx.x * 256 + threadIdx.x;     // 1,105,920 float4s
    float4 a = q4[i], b = p4[i];
    a.x += b.x; a.y += b.y; a.z += b.z; a.w += b.w;
    q4[i] = a;
    int row = i / 4608, c4 = i % 4608;
    if (c4 < 1536) {
        ushort4 u;
        u.x = f2bf(a.x); u.y = f2bf(a.y); u.z = f2bf(a.z); u.w = f2bf(a.w);
        *(ushort4*)(qb + (size_t)row * CC + c4 * 4) = u;
    }
}

// out += 3 partials + bias (in place)
__global__ __launch_bounds__(256)
void reduce_proj(float4* __restrict__ o4, const float4* __restrict__ p4,
                 long long s4, const float* __restrict__ bias) {
    int i = blockIdx.x * 256 + threadIdx.x;    // 368,640 float4s
    float4 a = o4[i];
#pragma unroll
    for (int k = 0; k < 3; ++k) {
        float4 b = p4[(size_t)k * s4 + i];
        a.x += b.x; a.y += b.y; a.z += b.z; a.w += b.w;
    }
    int c = (i % 1536) * 4;
    a.x += bias[c]; a.y += bias[c + 1]; a.z += bias[c + 2]; a.w += bias[c + 3];
    o4[i] = a;
}

// qmax[(h*240+n)*12 + c] = max over q[h][n][c*256 .. c*256+255]
__global__ __launch_bounds__(256)
void qmax_kernel(const float* __restrict__ qkv, float* __restrict__ qmax) {
    int idx = blockIdx.x * 4 + (threadIdx.x >> 6);   // 0..5759
    int lane = threadIdx.x & 63;
    int c = idx % 12;
    int r = idx / 12;            // h*240 + n
    int n = r % NN, h = r / NN;
    const float* p = qkv + (size_t)n * C3 + h * DD + c * 256 + lane * 4;
    float4 f = *(const float4*)p;
    float m = fmaxf(fmaxf(f.x, f.y), fmaxf(f.z, f.w));
#pragma unroll
    for (int off = 32; off >= 1; off >>= 1)
        m = fmaxf(m, __shfl_xor(m, off));
    if (lane == 0) qmax[idx] = m;
}

// Softmax rows of (scale * (attn + sum partials) + 0.1*Pq), in place.
__global__ __launch_bounds__(256)
void softmax_kernel(float* __restrict__ attn, const float* __restrict__ gpart,
                    int ksm1, const float* __restrict__ qmax) {
    int r = blockIdx.x * 4 + (threadIdx.x >> 6);   // 0..479 = z*240+n
    int lane = threadIdx.x & 63;
    int z = r / NN, n = r % NN;
    float* row = attn + (size_t)r * NN;
    const float* qm = qmax + r * 12;
    const float scale = 0.0180421959f;             // 3072^-0.5
    float v[4];
    float mx = -1e30f;
#pragma unroll
    for (int i = 0; i < 4; ++i) {
        int m = lane + 64 * i;
        v[i] = -1e30f;
        if (m < NN) {
            float s = row[m];
            for (int kc = 0; kc < ksm1; ++kc)
                s += gpart[(size_t)(z * ksm1 + kc) * (NN * NN)
                           + (size_t)n * NN + m];
            v[i] = s * scale + 0.1f * qm[m % 12];
        }
        mx = fmaxf(mx, v[i]);
    }
#pragma unroll
    for (int off = 32; off >= 1; off >>= 1)
        mx = fmaxf(mx, __shfl_xor(mx, off));
    float s = 0.f;
#pragma unroll
    for (int i = 0; i < 4; ++i) {
        v[i] = __expf(v[i] - mx);
        s += v[i];
    }
#pragma unroll
    for (int off = 32; off >= 1; off >>= 1)
        s += __shfl_xor(s, off);
    float inv = 1.0f / s;
#pragma unroll
    for (int i = 0; i < 4; ++i) {
        int m = lane + 64 * i;
        if (m < NN) row[m] = v[i] * inv;
    }
}

// preb[n][h*3072+dd] = bf16( sum_m attn[h][n][m] * v[h][m][dd] )
__global__ __launch_bounds__(256)
void pv_kernel(const float* __restrict__ attn, const float* __restrict__ qkv,
               ushort_t* __restrict__ preb) {
    const int h = blockIdx.z;
    const int n0 = blockIdx.y * 16;
    const int dd0 = blockIdx.x * 256;
    __shared__ float s_attn[16 * NN];
    for (int i = threadIdx.x; i < 16 * NN; i += 256)
        s_attn[i] = attn[(size_t)h * NN * NN + (n0 + i / NN) * NN + (i % NN)];
    __syncthreads();

    const float* vp = qkv + 2 * CC + h * DD + dd0 + threadIdx.x;
    float acc[16] = {};
    for (int m = 0; m < NN; m += 4) {
        float v0 = vp[(size_t)(m + 0) * C3];
        float v1 = vp[(size_t)(m + 1) * C3];
        float v2 = vp[(size_t)(m + 2) * C3];
        float v3 = vp[(size_t)(m + 3) * C3];
#pragma unroll
        for (int i = 0; i < 16; ++i) {
            float4 a = *(const float4*)&s_attn[i * NN + m];
            acc[i] += a.x * v0 + a.y * v1 + a.z * v2 + a.w * v3;
        }
    }
#pragma unroll
    for (int i = 0; i < 16; ++i)
        preb[(size_t)(n0 + i) * CC + h * DD + dd0 + threadIdx.x] =
            f2bf(acc[i]);
}

extern "C" void kernel_launch(void* const* d_in, const int* in_sizes, int n_in,
                              void* d_out, int out_size, void* d_ws, size_t ws_size,
                              hipStream_t stream) {
    const float* x      = (const float*)d_in[0];
    const float* w_qkv  = (const float*)d_in[1];
    const float* w_proj = (const float*)d_in[2];
    const float* b_proj = (const float*)d_in[3];
    float* out = (float*)d_out;

    // ws layout (floats): qkv 4.42M | attn 115K | qmax 5.8K | xb,qb,preb
    // (bf16 256x6144 each = 786K floats each) | gpart 4.42M  => 45.3 MB
    const size_t f_qkv  = (size_t)NN * C3;
    const size_t f_attn = (size_t)HH * NN * NN;
    const size_t f_qmax = (size_t)HH * NN * 12;
    float* qkv   = (float*)d_ws;
    float* attn  = qkv + f_qkv;
    float* qmaxb = attn + f_attn;
    ushort_t* xb   = (ushort_t*)(qmaxb + f_qmax);
    ushort_t* qb   = xb + (size_t)256 * CC;
    ushort_t* preb = qb + (size_t)256 * CC;
    float* gpart = (float*)(preb + (size_t)256 * CC);

    // 0. bf16 conversion of x + zero pad rows of qb/preb
    convert_kernel<<<864, 256, 0, stream>>>(x, xb, qb, preb);

    // 1. qkv = x @ w_qkv^T  (KS=2: kc0 -> qkv, kc1 -> gpart)
    gemm_as<<<dim3(C3 / 128, 1, 2), 512, 0, stream>>>(
        xb, CC, 0LL, w_qkv, CC, 0LL,
        qkv, 0LL, gpart, (long long)f_qkv,
        C3, C3, 3072, 2);
    reduce_qkv<<<4320, 256, 0, stream>>>((float4*)qkv, (const float4*)gpart, qb);

    // 2. Pq maxpool over q
    qmax_kernel<<<1440, 256, 0, stream>>>(qkv, qmaxb);

    // 3. attn_raw = Q @ K^T per head (KS=24; kc0 -> attn, rest -> gpart)
    gemm_as<<<dim3(2, 1, HH * 24), 512, 0, stream>>>(
        qb, CC, (long long)DD,
        qkv + CC, C3, (long long)DD,
        attn, (long long)(NN * NN), gpart, (long long)(NN * NN),
        NN, NN, 128, 24);

    // 4. softmax (fuses split-K reduce, scale, +0.1*Pq)
    softmax_kernel<<<120, 256, 0, stream>>>(attn, gpart, 23, qmaxb);

    // 5. preb = bf16(attn @ V)
    pv_kernel<<<dim3(12, 15, HH), 256, 0, stream>>>(attn, qkv, preb);

    // 6. out = pre @ w_proj^T + b_proj (KS=4: kc0 -> out, rest -> gpart)
    gemm_as<<<dim3(CC / 128, 1, 4), 512, 0, stream>>>(
        preb, CC, 0LL, w_proj, CC, 0LL,
        out, 0LL, gpart, (long long)((size_t)NN * CC),
        CC, CC, 1536, 4);
    reduce_proj<<<1440, 256, 0, stream>>>((float4*)out, (const float4*)gpart,
        (long long)((size_t)NN * CC / 4), b_proj);
}

// Round 4
// 354.155 us; speedup vs baseline: 1.6421x; 1.6421x over previous
//
#include <hip/hip_runtime.h>
#include <hip/hip_bf16.h>

// Problem constants
#define NN 240        // rows (tokens)
#define CC 6144       // channels
#define DD 3072       // head dim
#define C3 18432      // 3*C
#define HH 2          // heads

typedef __attribute__((ext_vector_type(8))) short bf16x8;
typedef __attribute__((ext_vector_type(4))) float f32x4;
typedef unsigned short ushort_t;

static __device__ __forceinline__ unsigned short f2bf(float f) {
    __hip_bfloat16 h = __float2bfloat16(f);
    return __builtin_bit_cast(unsigned short, h);
}

// global -> LDS direct DMA, 16 B per lane, LDS dest wave-uniform base.
#define GLDS16(g, l) __builtin_amdgcn_global_load_lds( \
    (const __attribute__((address_space(1))) void*)(g), \
    (__attribute__((address_space(3))) void*)(l), 16, 0, 0)

// C[240 x N] = A_bf16[256 x K] * B_fp32[N x K]^T (+bias on kc==0), split-K.
// BM=256 (all rows), BN=64, BK=64. 8 waves (4M x 2N), per-wave 64x32.
// A staged via global_load_lds (source pre-XOR-swizzled, LDS linear);
// B staged global->reg->cvt->ds_write into the SAME proven bf16 layout
// (8x16B slots per 128B row, slot ^= row&7  -> zero bank conflicts).
__global__ __launch_bounds__(512, 4)
void gemm_bt4(const ushort_t* __restrict__ Ab, int lda, long long sAz,
              const float* __restrict__ B, int ldb, long long sBz,
              const float* __restrict__ bias,
              float* __restrict__ C0, long long sC0z,
              float* __restrict__ CP, long long sCPz,
              int ldc, int N, int Kc, int KS,
              ushort_t* __restrict__ Qb) {
    __shared__ ushort_t sA[2][256 * 64];   // 2 x 32 KB
    __shared__ ushort_t sB[2][64 * 64];    // 2 x 8 KB   (total 80 KB -> 2 blk/CU)

    const int zc = blockIdx.z;
    const int z = zc / KS, kc = zc % KS;
    const ushort_t* Abase = Ab + (size_t)z * sAz + (size_t)kc * Kc;
    const float*    Bbase = B  + (size_t)z * sBz + (size_t)kc * Kc;
    float* Cw = (kc == 0) ? (C0 + (size_t)z * sC0z)
                          : (CP + (size_t)(z * (KS - 1) + kc - 1) * sCPz);

    const int n0 = blockIdx.x * 64;
    const int tid = threadIdx.x, lane = tid & 63, wid = tid >> 6;
    const int wm = wid >> 1, wn = wid & 1;
    const int l16 = lane & 15, lk = lane >> 4;

    // A DMA: wave w, i=0..3 -> chunk c=w*4+i covers rows c*8..c*8+7 (128 B/row).
    // Lane l -> row c*8+(l>>3), stored slot l&7 holds source octet (l&7)^(row&7).
    const int arow = wid * 32 + (lane >> 3);
    const ushort_t* ap = Abase + (size_t)arow * lda
                         + ((lane & 7) ^ ((lane >> 3) & 7)) * 8;

    // B stage: thread t -> row t>>3 (0..63), octet t&7 (8 consecutive floats).
    const int brow = tid >> 3, boct = tid & 7;
    const float* bp = Bbase + (size_t)(n0 + brow) * ldb + boct * 8;
    const int bws = brow * 64 + ((boct ^ (brow & 7)) * 8);   // swizzled elem idx

    f32x4 acc[4][2] = {};
    const int nt = Kc / 64;

    // prologue: stage tile 0 into buffer 0
    {
#pragma unroll
        for (int i = 0; i < 4; ++i)
            GLDS16(ap + (size_t)i * 8 * lda, &sA[0][(wid * 4 + i) * 512]);
        float4 f0 = *(const float4*)bp;
        float4 f1 = *(const float4*)(bp + 4);
        asm volatile("s_waitcnt vmcnt(0)" ::: "memory");
        bf16x8 r;
        r[0] = (short)f2bf(f0.x); r[1] = (short)f2bf(f0.y);
        r[2] = (short)f2bf(f0.z); r[3] = (short)f2bf(f0.w);
        r[4] = (short)f2bf(f1.x); r[5] = (short)f2bf(f1.y);
        r[6] = (short)f2bf(f1.z); r[7] = (short)f2bf(f1.w);
        *(bf16x8*)&sB[0][bws] = r;
        __syncthreads();
    }

    for (int t = 0; t < nt; ++t) {
        const int cur = t & 1, nxt = cur ^ 1;
        const bool pf = (t + 1 < nt);
        float4 f0, f1;
        if (pf) {   // issue next tile's A-DMA + B global loads NOW
            const ushort_t* a = ap + (size_t)(t + 1) * 64;
#pragma unroll
            for (int i = 0; i < 4; ++i)
                GLDS16(a + (size_t)i * 8 * lda, &sA[nxt][(wid * 4 + i) * 512]);
            const float* p = bp + (size_t)(t + 1) * 64;
            f0 = *(const float4*)p;
            f1 = *(const float4*)(p + 4);
        }
        __builtin_amdgcn_sched_barrier(0);   // pin load issue before MFMA phase

        const char* As = (const char*)sA[cur];
        const char* Bs = (const char*)sB[cur];
#pragma unroll
        for (int ks = 0; ks < 2; ++ks) {
            bf16x8 af[4], bf[2];
#pragma unroll
            for (int mt = 0; mt < 4; ++mt) {
                int row = wm * 64 + mt * 16 + l16;
                int boff = row * 128 + (((ks * 4 + lk) * 16) ^ ((row & 7) << 4));
                af[mt] = *(const bf16x8*)(As + boff);
            }
#pragma unroll
            for (int nf = 0; nf < 2; ++nf) {
                int row = wn * 32 + nf * 16 + l16;
                int boff = row * 128 + (((ks * 4 + lk) * 16) ^ ((row & 7) << 4));
                bf[nf] = *(const bf16x8*)(Bs + boff);
            }
            __builtin_amdgcn_s_setprio(1);
#pragma unroll
            for (int mt = 0; mt < 4; ++mt)
#pragma unroll
                for (int nf = 0; nf < 2; ++nf)
                    acc[mt][nf] = __builtin_amdgcn_mfma_f32_16x16x32_bf16(
                        af[mt], bf[nf], acc[mt][nf], 0, 0, 0);
            __builtin_amdgcn_s_setprio(0);
        }
        __builtin_amdgcn_sched_barrier(0);

        if (pf) {
            asm volatile("s_waitcnt vmcnt(0)" ::: "memory");  // A DMA + B regs done
            bf16x8 r;
            r[0] = (short)f2bf(f0.x); r[1] = (short)f2bf(f0.y);
            r[2] = (short)f2bf(f0.z); r[3] = (short)f2bf(f0.w);
            r[4] = (short)f2bf(f1.x); r[5] = (short)f2bf(f1.y);
            r[6] = (short)f2bf(f1.z); r[7] = (short)f2bf(f1.w);
            *(bf16x8*)&sB[nxt][bws] = r;
        }
        __syncthreads();
    }

    // Epilogue: fragment row = lk*4+j, col = l16
#pragma unroll
    for (int mt = 0; mt < 4; ++mt) {
#pragma unroll
        for (int j = 0; j < 4; ++j) {
            int grow = wm * 64 + mt * 16 + lk * 4 + j;
            if (grow < NN) {
#pragma unroll
                for (int nf = 0; nf < 2; ++nf) {
                    int gcol = n0 + wn * 32 + nf * 16 + l16;
                    if (gcol < N) {
                        float v = acc[mt][nf][j];
                        if (kc == 0 && bias) v += bias[gcol];
                        Cw[(size_t)grow * ldc + gcol] = v;
                        if (Qb && gcol < CC)
                            Qb[(size_t)grow * CC + gcol] = f2bf(v);
                    }
                }
            }
        }
    }
}

// xb = bf16(x), rows 240..255 zeroed.
__global__ __launch_bounds__(256)
void convert_kernel(const float* __restrict__ x, ushort_t* __restrict__ xb) {
    int id = blockIdx.x * 256 + threadIdx.x;      // 196608 = 256*6144/8
    int row = id / 768, c8 = id % 768;
    bf16x8 o = {};
    if (row < NN) {
        const float* p = x + (size_t)row * CC + c8 * 8;
        float4 a = *(const float4*)p, b = *(const float4*)(p + 4);
        o[0] = (short)f2bf(a.x); o[1] = (short)f2bf(a.y);
        o[2] = (short)f2bf(a.z); o[3] = (short)f2bf(a.w);
        o[4] = (short)f2bf(b.x); o[5] = (short)f2bf(b.y);
        o[6] = (short)f2bf(b.z); o[7] = (short)f2bf(b.w);
    }
    *(bf16x8*)(xb + (size_t)row * CC + c8 * 8) = o;
}

// out += 2 partials (proj split-K reduce; bias already added by kc==0 path)
__global__ __launch_bounds__(256)
void reduce_proj(float4* __restrict__ o4, const float4* __restrict__ p4,
                 long long s4) {
    int i = blockIdx.x * 256 + threadIdx.x;    // 368,640 float4s
    float4 a = o4[i];
#pragma unroll
    for (int k = 0; k < 2; ++k) {
        float4 b = p4[(size_t)k * s4 + i];
        a.x += b.x; a.y += b.y; a.z += b.z; a.w += b.w;
    }
    o4[i] = a;
}

// qmax[(h*240+n)*12 + c] = max over q[h][n][c*256 .. c*256+255]
__global__ __launch_bounds__(256)
void qmax_kernel(const float* __restrict__ qkv, float* __restrict__ qmax) {
    int idx = blockIdx.x * 4 + (threadIdx.x >> 6);   // 0..5759
    int lane = threadIdx.x & 63;
    int c = idx % 12;
    int r = idx / 12;            // h*240 + n
    int n = r % NN, h = r / NN;
    const float* p = qkv + (size_t)n * C3 + h * DD + c * 256 + lane * 4;
    float4 f = *(const float4*)p;
    float m = fmaxf(fmaxf(f.x, f.y), fmaxf(f.z, f.w));
#pragma unroll
    for (int off = 32; off >= 1; off >>= 1)
        m = fmaxf(m, __shfl_xor(m, off));
    if (lane == 0) qmax[idx] = m;
}

// Softmax rows of (scale * (attn + sum partials) + 0.1*Pq), in place.
__global__ __launch_bounds__(256)
void softmax_kernel(float* __restrict__ attn, const float* __restrict__ gpart,
                    int ksm1, const float* __restrict__ qmax) {
    int r = blockIdx.x * 4 + (threadIdx.x >> 6);   // 0..479 = z*240+n
    int lane = threadIdx.x & 63;
    int z = r / NN, n = r % NN;
    float* row = attn + (size_t)r * NN;
    const float* qm = qmax + r * 12;
    const float scale = 0.0180421959f;             // 3072^-0.5
    float v[4];
    float mx = -1e30f;
#pragma unroll
    for (int i = 0; i < 4; ++i) {
        int m = lane + 64 * i;
        v[i] = -1e30f;
        if (m < NN) {
            float s = row[m];
            for (int kc = 0; kc < ksm1; ++kc)
                s += gpart[(size_t)(z * ksm1 + kc) * (NN * NN)
                           + (size_t)n * NN + m];
            v[i] = s * scale + 0.1f * qm[m % 12];
        }
        mx = fmaxf(mx, v[i]);
    }
#pragma unroll
    for (int off = 32; off >= 1; off >>= 1)
        mx = fmaxf(mx, __shfl_xor(mx, off));
    float s = 0.f;
#pragma unroll
    for (int i = 0; i < 4; ++i) {
        v[i] = __expf(v[i] - mx);
        s += v[i];
    }
#pragma unroll
    for (int off = 32; off >= 1; off >>= 1)
        s += __shfl_xor(s, off);
    float inv = 1.0f / s;
#pragma unroll
    for (int i = 0; i < 4; ++i) {
        int m = lane + 64 * i;
        if (m < NN) row[m] = v[i] * inv;
    }
}

// preb[n][h*3072+dd] = bf16( sum_m attn[h][n][m] * v[h][m][dd] )
__global__ __launch_bounds__(256)
void pv_kernel(const float* __restrict__ attn, const float* __restrict__ qkv,
               ushort_t* __restrict__ preb) {
    const int h = blockIdx.z;
    const int n0 = blockIdx.y * 16;
    const int dd0 = blockIdx.x * 256;
    __shared__ float s_attn[16 * NN];
    for (int i = threadIdx.x; i < 16 * NN; i += 256)
        s_attn[i] = attn[(size_t)h * NN * NN + (n0 + i / NN) * NN + (i % NN)];
    __syncthreads();

    const float* vp = qkv + 2 * CC + h * DD + dd0 + threadIdx.x;
    float acc[16] = {};
    for (int m = 0; m < NN; m += 4) {
        float v0 = vp[(size_t)(m + 0) * C3];
        float v1 = vp[(size_t)(m + 1) * C3];
        float v2 = vp[(size_t)(m + 2) * C3];
        float v3 = vp[(size_t)(m + 3) * C3];
#pragma unroll
        for (int i = 0; i < 16; ++i) {
            float4 a = *(const float4*)&s_attn[i * NN + m];
            acc[i] += a.x * v0 + a.y * v1 + a.z * v2 + a.w * v3;
        }
    }
#pragma unroll
    for (int i = 0; i < 16; ++i)
        preb[(size_t)(n0 + i) * CC + h * DD + dd0 + threadIdx.x] =
            f2bf(acc[i]);
}

extern "C" void kernel_launch(void* const* d_in, const int* in_sizes, int n_in,
                              void* d_out, int out_size, void* d_ws, size_t ws_size,
                              hipStream_t stream) {
    const float* x      = (const float*)d_in[0];
    const float* w_qkv  = (const float*)d_in[1];
    const float* w_proj = (const float*)d_in[2];
    const float* b_proj = (const float*)d_in[3];
    float* out = (float*)d_out;

    // ws layout (floats): qkv 4.42M | attn 115K | qmax 5.8K |
    // xb,qb,preb (bf16 256x6144 each) | gpart 4.42M   => ~45.3 MB (fits, r3 ran)
    const size_t f_qkv  = (size_t)NN * C3;
    const size_t f_attn = (size_t)HH * NN * NN;
    const size_t f_qmax = (size_t)HH * NN * 12;
    float* qkv   = (float*)d_ws;
    float* attn  = qkv + f_qkv;
    float* qmaxb = attn + f_attn;
    ushort_t* xb   = (ushort_t*)(qmaxb + f_qmax);
    ushort_t* qb   = xb + (size_t)256 * CC;
    ushort_t* preb = qb + (size_t)256 * CC;
    float* gpart = (float*)(preb + (size_t)256 * CC);

    // 0. bf16 conversion of x (zero-padded to 256 rows)
    convert_kernel<<<768, 256, 0, stream>>>(x, xb);

    // 1. qkv = x @ w_qkv^T  (KS=1, 288 blocks; epilogue also emits bf16 Q)
    gemm_bt4<<<dim3(C3 / 64, 1, 1), 512, 0, stream>>>(
        xb, CC, 0LL, w_qkv, CC, 0LL, nullptr,
        qkv, 0LL, gpart, 0LL,
        C3, C3, CC, 1, qb);

    // 2. Pq maxpool over q
    qmax_kernel<<<1440, 256, 0, stream>>>(qkv, qmaxb);

    // 3. attn_raw = Q @ K^T per head (KS=16: kc0 -> attn, rest -> gpart)
    gemm_bt4<<<dim3(4, 1, HH * 16), 512, 0, stream>>>(
        qb, CC, (long long)DD,
        qkv + CC, C3, (long long)DD, nullptr,
        attn, (long long)(NN * NN), gpart, (long long)(NN * NN),
        NN, NN, DD / 16, 16, nullptr);

    // 4. softmax (fuses split-K reduce, scale, +0.1*Pq)
    softmax_kernel<<<120, 256, 0, stream>>>(attn, gpart, 15, qmaxb);

    // 5. preb = bf16(attn @ V)
    pv_kernel<<<dim3(12, 15, HH), 256, 0, stream>>>(attn, qkv, preb);

    // 6. out = pre @ w_proj^T + b_proj (KS=3: kc0 -> out+bias, rest -> gpart)
    gemm_bt4<<<dim3(CC / 64, 1, 3), 512, 0, stream>>>(
        preb, CC, 0LL, w_proj, CC, 0LL, b_proj,
        out, 0LL, gpart, (long long)((size_t)NN * CC),
        CC, CC, CC / 3, 3, nullptr);
    reduce_proj<<<1440, 256, 0, stream>>>((float4*)out, (const float4*)gpart,
        (long long)((size_t)NN * CC / 4));
}

// Round 5
// 341.581 us; speedup vs baseline: 1.7026x; 1.0368x over previous
//
#include <hip/hip_runtime.h>
#include <hip/hip_bf16.h>

// Problem constants
#define NN 240        // rows (tokens)
#define CC 6144       // channels
#define DD 3072       // head dim
#define C3 18432      // 3*C
#define HH 2          // heads

typedef __attribute__((ext_vector_type(8))) short bf16x8;
typedef __attribute__((ext_vector_type(4))) float f32x4;
typedef unsigned short ushort_t;

static __device__ __forceinline__ unsigned short f2bf(float f) {
    __hip_bfloat16 h = __float2bfloat16(f);
    return __builtin_bit_cast(unsigned short, h);
}

// global -> LDS direct DMA, 16 B per lane, LDS dest wave-uniform base.
#define GLDS16(g, l) __builtin_amdgcn_global_load_lds( \
    (const __attribute__((address_space(1))) void*)(g), \
    (__attribute__((address_space(3))) void*)(l), 16, 0, 0)

// C[240 x N] = A_bf16[256 x K] * B_fp32[N x K]^T (+bias on kc==0), split-K.
// BM=256 (all rows), BN=64, BK=64. 8 waves (4M x 2N), per-wave 64x32.
// Pipeline: A depth-1 via global_load_lds (L2-resident operand, ~200cy);
// B depth-2 via regs (HBM stream, ~900cy) -> per-step wait is vmcnt(2)
// (B(t+2) stays in flight across the barrier), raw s_barrier + lgkmcnt(0).
__global__ __launch_bounds__(512, 4)
void gemm_p2(const ushort_t* __restrict__ Ab, int lda, long long sAz,
             const float* __restrict__ B, int ldb, long long sBz,
             const float* __restrict__ bias,
             float* __restrict__ C0, long long sC0z,
             float* __restrict__ CP, long long sCPz,
             int ldc, int N, int Kc, int KS,
             ushort_t* __restrict__ Qb) {
    __shared__ ushort_t sA[2][256 * 64];   // 2 x 32 KB
    __shared__ ushort_t sB[2][64 * 64];    // 2 x 8 KB  (80 KB -> 2 blk/CU)

    const int zc = blockIdx.z;
    const int z = zc / KS, kc = zc % KS;
    const ushort_t* Abase = Ab + (size_t)z * sAz + (size_t)kc * Kc;
    const float*    Bbase = B  + (size_t)z * sBz + (size_t)kc * Kc;
    float* Cw = (kc == 0) ? (C0 + (size_t)z * sC0z)
                          : (CP + (size_t)(z * (KS - 1) + kc - 1) * sCPz);

    const int n0 = blockIdx.x * 64;
    const int tid = threadIdx.x, lane = tid & 63, wid = tid >> 6;
    const int wm = wid >> 1, wn = wid & 1;
    const int l16 = lane & 15, lk = lane >> 4;

    // A DMA source: chunk c=wid*4+i covers LDS rows c*8..c*8+7 (128 B/row).
    // Lane l -> row c*8+(l>>3); stored slot l&7 holds source octet (l&7)^(row&7)
    // so the XOR'd ds_read below recovers linear k. (Proven zero-conflict.)
    const int arow = wid * 32 + (lane >> 3);
    const ushort_t* ap = Abase + (size_t)arow * lda
                         + ((lane & 7) ^ ((lane >> 3) & 7)) * 8;

    // B stage: thread t -> row t>>3 (0..63), octet t&7 (8 consecutive floats).
    const int brow = tid >> 3, boct = tid & 7;
    const float* bp = Bbase + (size_t)(n0 + brow) * ldb + boct * 8;
    const int bws = brow * 64 + ((boct ^ (brow & 7)) * 8);   // swizzled elem idx

    const int nt = Kc / 64;                 // even by construction
    f32x4 acc[4][2] = {};

    auto ISSUE_A = [&](int t) {
        const ushort_t* a = ap + (size_t)t * 64;
#pragma unroll
        for (int i = 0; i < 4; ++i)
            GLDS16(a + (size_t)i * 8 * lda, &sA[t & 1][(wid * 4 + i) * 512]);
    };
    auto LOAD_B = [&](int t, float4& g0, float4& g1) {
        const float* p = bp + (size_t)t * 64;
        g0 = *(const float4*)p;
        g1 = *(const float4*)(p + 4);
    };
    auto WRITE_B = [&](int t, float4& g0, float4& g1) {
        bf16x8 r;
        r[0] = (short)f2bf(g0.x); r[1] = (short)f2bf(g0.y);
        r[2] = (short)f2bf(g0.z); r[3] = (short)f2bf(g0.w);
        r[4] = (short)f2bf(g1.x); r[5] = (short)f2bf(g1.y);
        r[6] = (short)f2bf(g1.z); r[7] = (short)f2bf(g1.w);
        *(bf16x8*)&sB[t & 1][bws] = r;
    };
    auto MFMA_PH = [&](int t) {
        const char* As = (const char*)sA[t & 1];
        const char* Bs = (const char*)sB[t & 1];
#pragma unroll
        for (int ks = 0; ks < 2; ++ks) {
            bf16x8 af[4], bf[2];
#pragma unroll
            for (int mt = 0; mt < 4; ++mt) {
                int row = wm * 64 + mt * 16 + l16;
                int boff = row * 128 + (((ks * 4 + lk) * 16) ^ ((row & 7) << 4));
                af[mt] = *(const bf16x8*)(As + boff);
            }
#pragma unroll
            for (int nf = 0; nf < 2; ++nf) {
                int row = wn * 32 + nf * 16 + l16;
                int boff = row * 128 + (((ks * 4 + lk) * 16) ^ ((row & 7) << 4));
                bf[nf] = *(const bf16x8*)(Bs + boff);
            }
            __builtin_amdgcn_s_setprio(1);
#pragma unroll
            for (int mt = 0; mt < 4; ++mt)
#pragma unroll
                for (int nf = 0; nf < 2; ++nf)
                    acc[mt][nf] = __builtin_amdgcn_mfma_f32_16x16x32_bf16(
                        af[mt], bf[nf], acc[mt][nf], 0, 0, 0);
            __builtin_amdgcn_s_setprio(0);
        }
    };

    float4 e0, e1, o0, o1;    // static even/odd B register sets (rule #20)

    // prologue: A(0) DMA, B(0)+B(1) regs; flush B(0); barrier
    ISSUE_A(0);
    LOAD_B(0, e0, e1);
    if (nt > 1) {
        LOAD_B(1, o0, o1);
        asm volatile("s_waitcnt vmcnt(2)" ::: "memory");   // A(0),B(0) done
    } else {
        asm volatile("s_waitcnt vmcnt(0)" ::: "memory");
    }
    __builtin_amdgcn_sched_barrier(0);
    WRITE_B(0, e0, e1);
    asm volatile("s_waitcnt lgkmcnt(0)" ::: "memory");
    __builtin_amdgcn_s_barrier();

    // STEP(t): recv B(t+2) into (w0,w1); flush B(t+1) from (r0,r1)
    auto STEP = [&](int t, float4& w0, float4& w1, float4& r0, float4& r1) {
        const bool ia = (t + 1 < nt);
        const bool ib = (t + 2 < nt);
        if (ia) ISSUE_A(t + 1);
        if (ib) LOAD_B(t + 2, w0, w1);
        __builtin_amdgcn_sched_barrier(0);
        MFMA_PH(t);
        __builtin_amdgcn_sched_barrier(0);
        if (ib) asm volatile("s_waitcnt vmcnt(2)" ::: "memory"); // B(t+1),A(t+1) done
        else    asm volatile("s_waitcnt vmcnt(0)" ::: "memory");
        __builtin_amdgcn_sched_barrier(0);
        if (ia) WRITE_B(t + 1, r0, r1);
        asm volatile("s_waitcnt lgkmcnt(0)" ::: "memory");
        __builtin_amdgcn_s_barrier();
    };

    for (int t = 0; t < nt; t += 2) {
        STEP(t,     e0, e1, o0, o1);
        STEP(t + 1, o0, o1, e0, e1);
    }

    // Epilogue: fragment row = lk*4+j, col = l16
#pragma unroll
    for (int mt = 0; mt < 4; ++mt) {
#pragma unroll
        for (int j = 0; j < 4; ++j) {
            int grow = wm * 64 + mt * 16 + lk * 4 + j;
            if (grow < NN) {
#pragma unroll
                for (int nf = 0; nf < 2; ++nf) {
                    int gcol = n0 + wn * 32 + nf * 16 + l16;
                    if (gcol < N) {
                        float v = acc[mt][nf][j];
                        if (kc == 0 && bias) v += bias[gcol];
                        Cw[(size_t)grow * ldc + gcol] = v;
                        if (Qb && gcol < CC)
                            Qb[(size_t)grow * CC + gcol] = f2bf(v);
                    }
                }
            }
        }
    }
}

// xb = bf16(x), rows 240..255 zeroed.
__global__ __launch_bounds__(256)
void convert_kernel(const float* __restrict__ x, ushort_t* __restrict__ xb) {
    int id = blockIdx.x * 256 + threadIdx.x;      // 196608 = 256*6144/8
    int row = id / 768, c8 = id % 768;
    bf16x8 o = {};
    if (row < NN) {
        const float* p = x + (size_t)row * CC + c8 * 8;
        float4 a = *(const float4*)p, b = *(const float4*)(p + 4);
        o[0] = (short)f2bf(a.x); o[1] = (short)f2bf(a.y);
        o[2] = (short)f2bf(a.z); o[3] = (short)f2bf(a.w);
        o[4] = (short)f2bf(b.x); o[5] = (short)f2bf(b.y);
        o[6] = (short)f2bf(b.z); o[7] = (short)f2bf(b.w);
    }
    *(bf16x8*)(xb + (size_t)row * CC + c8 * 8) = o;
}

// out += 2 partials (proj split-K reduce; bias added by kc==0 path)
__global__ __launch_bounds__(256)
void reduce_proj(float4* __restrict__ o4, const float4* __restrict__ p4,
                 long long s4) {
    int i = blockIdx.x * 256 + threadIdx.x;    // 368,640 float4s
    float4 a = o4[i];
#pragma unroll
    for (int k = 0; k < 2; ++k) {
        float4 b = p4[(size_t)k * s4 + i];
        a.x += b.x; a.y += b.y; a.z += b.z; a.w += b.w;
    }
    o4[i] = a;
}

// qmax[(h*240+n)*12 + c] = max over q[h][n][c*256 .. c*256+255]
__global__ __launch_bounds__(256)
void qmax_kernel(const float* __restrict__ qkv, float* __restrict__ qmax) {
    int idx = blockIdx.x * 4 + (threadIdx.x >> 6);   // 0..5759
    int lane = threadIdx.x & 63;
    int c = idx % 12;
    int r = idx / 12;            // h*240 + n
    int n = r % NN, h = r / NN;
    const float* p = qkv + (size_t)n * C3 + h * DD + c * 256 + lane * 4;
    float4 f = *(const float4*)p;
    float m = fmaxf(fmaxf(f.x, f.y), fmaxf(f.z, f.w));
#pragma unroll
    for (int off = 32; off >= 1; off >>= 1)
        m = fmaxf(m, __shfl_xor(m, off));
    if (lane == 0) qmax[idx] = m;
}

// Softmax rows of (scale * (attn + sum partials) + 0.1*Pq), in place.
__global__ __launch_bounds__(256)
void softmax_kernel(float* __restrict__ attn, const float* __restrict__ gpart,
                    int ksm1, const float* __restrict__ qmax) {
    int r = blockIdx.x * 4 + (threadIdx.x >> 6);   // 0..479 = z*240+n
    int lane = threadIdx.x & 63;
    int z = r / NN, n = r % NN;
    float* row = attn + (size_t)r * NN;
    const float* qm = qmax + r * 12;
    const float scale = 0.0180421959f;             // 3072^-0.5
    float v[4];
    float mx = -1e30f;
#pragma unroll
    for (int i = 0; i < 4; ++i) {
        int m = lane + 64 * i;
        v[i] = -1e30f;
        if (m < NN) {
            float s = row[m];
            for (int kc = 0; kc < ksm1; ++kc)
                s += gpart[(size_t)(z * ksm1 + kc) * (NN * NN)
                           + (size_t)n * NN + m];
            v[i] = s * scale + 0.1f * qm[m % 12];
        }
        mx = fmaxf(mx, v[i]);
    }
#pragma unroll
    for (int off = 32; off >= 1; off >>= 1)
        mx = fmaxf(mx, __shfl_xor(mx, off));
    float s = 0.f;
#pragma unroll
    for (int i = 0; i < 4; ++i) {
        v[i] = __expf(v[i] - mx);
        s += v[i];
    }
#pragma unroll
    for (int off = 32; off >= 1; off >>= 1)
        s += __shfl_xor(s, off);
    float inv = 1.0f / s;
#pragma unroll
    for (int i = 0; i < 4; ++i) {
        int m = lane + 64 * i;
        if (m < NN) row[m] = v[i] * inv;
    }
}

// preb[n][h*3072+dd] = bf16( sum_m attn[h][n][m] * v[h][m][dd] )
__global__ __launch_bounds__(256)
void pv_kernel(const float* __restrict__ attn, const float* __restrict__ qkv,
               ushort_t* __restrict__ preb) {
    const int h = blockIdx.z;
    const int n0 = blockIdx.y * 16;
    const int dd0 = blockIdx.x * 256;
    __shared__ float s_attn[16 * NN];
    for (int i = threadIdx.x; i < 16 * NN; i += 256)
        s_attn[i] = attn[(size_t)h * NN * NN + (n0 + i / NN) * NN + (i % NN)];
    __syncthreads();

    const float* vp = qkv + 2 * CC + h * DD + dd0 + threadIdx.x;
    float acc[16] = {};
    for (int m = 0; m < NN; m += 4) {
        float v0 = vp[(size_t)(m + 0) * C3];
        float v1 = vp[(size_t)(m + 1) * C3];
        float v2 = vp[(size_t)(m + 2) * C3];
        float v3 = vp[(size_t)(m + 3) * C3];
#pragma unroll
        for (int i = 0; i < 16; ++i) {
            float4 a = *(const float4*)&s_attn[i * NN + m];
            acc[i] += a.x * v0 + a.y * v1 + a.z * v2 + a.w * v3;
        }
    }
#pragma unroll
    for (int i = 0; i < 16; ++i)
        preb[(size_t)(n0 + i) * CC + h * DD + dd0 + threadIdx.x] =
            f2bf(acc[i]);
}

extern "C" void kernel_launch(void* const* d_in, const int* in_sizes, int n_in,
                              void* d_out, int out_size, void* d_ws, size_t ws_size,
                              hipStream_t stream) {
    const float* x      = (const float*)d_in[0];
    const float* w_qkv  = (const float*)d_in[1];
    const float* w_proj = (const float*)d_in[2];
    const float* b_proj = (const float*)d_in[3];
    float* out = (float*)d_out;

    // ws layout (floats): qkv 4.42M | attn 115K | qmax 5.8K |
    // xb,qb,preb (bf16 256x6144 each) | gpart 4.42M   => ~45.3 MB
    const size_t f_qkv  = (size_t)NN * C3;
    const size_t f_attn = (size_t)HH * NN * NN;
    const size_t f_qmax = (size_t)HH * NN * 12;
    float* qkv   = (float*)d_ws;
    float* attn  = qkv + f_qkv;
    float* qmaxb = attn + f_attn;
    ushort_t* xb   = (ushort_t*)(qmaxb + f_qmax);
    ushort_t* qb   = xb + (size_t)256 * CC;
    ushort_t* preb = qb + (size_t)256 * CC;
    float* gpart = (float*)(preb + (size_t)256 * CC);

    // 0. bf16 conversion of x (zero-padded to 256 rows)
    convert_kernel<<<768, 256, 0, stream>>>(x, xb);

    // 1. qkv = x @ w_qkv^T  (KS=1, 288 blocks, nt=96; epilogue emits bf16 Q)
    gemm_p2<<<dim3(C3 / 64, 1, 1), 512, 0, stream>>>(
        xb, CC, 0LL, w_qkv, CC, 0LL, nullptr,
        qkv, 0LL, gpart, 0LL,
        C3, C3, CC, 1, qb);

    // 2. Pq maxpool over q
    qmax_kernel<<<1440, 256, 0, stream>>>(qkv, qmaxb);

    // 3. attn_raw = Q @ K^T per head (KS=24, nt=2: kc0 -> attn, rest -> gpart)
    gemm_p2<<<dim3(4, 1, HH * 24), 512, 0, stream>>>(
        qb, CC, (long long)DD,
        qkv + CC, C3, (long long)DD, nullptr,
        attn, (long long)(NN * NN), gpart, (long long)(NN * NN),
        NN, NN, DD / 24, 24, nullptr);

    // 4. softmax (fuses split-K reduce, scale, +0.1*Pq)
    softmax_kernel<<<120, 256, 0, stream>>>(attn, gpart, 23, qmaxb);

    // 5. preb = bf16(attn @ V)
    pv_kernel<<<dim3(12, 15, HH), 256, 0, stream>>>(attn, qkv, preb);

    // 6. out = pre @ w_proj^T + b_proj (KS=3, nt=32: kc0 -> out+bias)
    gemm_p2<<<dim3(CC / 64, 1, 3), 512, 0, stream>>>(
        preb, CC, 0LL, w_proj, CC, 0LL, b_proj,
        out, 0LL, gpart, (long long)((size_t)NN * CC),
        CC, CC, CC / 3, 3, nullptr);
    reduce_proj<<<1440, 256, 0, stream>>>((float4*)out, (const float4*)gpart,
        (long long)((size_t)NN * CC / 4));
}